// Round 5
// baseline (229.159 us; speedup 1.0000x reference)
//
#include <hip/hip_runtime.h>
#include <stdint.h>
#include <stddef.h>

#define NB 4
#define NS 2048
#define ND 1024
#define NH 16
#define HDIM 64
#define SCALE 0.125f

typedef __attribute__((ext_vector_type(4))) float f32x4;
typedef __attribute__((ext_vector_type(16))) float f32x16;
typedef __attribute__((ext_vector_type(8))) __bf16 bf16x8;
typedef __attribute__((ext_vector_type(4))) uint32_t u32x4;

__device__ __forceinline__ uint16_t f2bf(float f) {
  uint32_t u = __builtin_bit_cast(uint32_t, f);
  return (uint16_t)((u + 0x7fffu + ((u >> 16) & 1u)) >> 16);
}

__device__ __forceinline__ void gload_lds16(const void* g, void* l) {
  __builtin_amdgcn_global_load_lds((const __attribute__((address_space(1))) void*)g,
                                   (__attribute__((address_space(3))) void*)l, 16, 0, 0);
}

__device__ __forceinline__ uint32_t cvtpk(float lo, float hi) {
  uint32_t r;
  asm("v_cvt_pk_bf16_f32 %0, %1, %2" : "=v"(r) : "v"(lo), "v"(hi));
  return r;
}

__device__ __forceinline__ void permswap(uint32_t& a, uint32_t& b) {
  asm("v_permlane32_swap_b32 %0, %1" : "+v"(a), "+v"(b));
}

__device__ __forceinline__ float fexp2(float x) {
  float r;
  asm("v_exp_f32 %0, %1" : "=v"(r) : "v"(x));
  return r;
}

// ---------------- fp32 -> bf16 elementwise ----------------
__global__ void k_cvt_bf16(const float* __restrict__ in, uint16_t* __restrict__ out, int n4) {
  int i = blockIdx.x * blockDim.x + threadIdx.x;
  if (i >= n4) return;
  float4 v = reinterpret_cast<const float4*>(in)[i];
  ushort4 o;
  o.x = f2bf(v.x); o.y = f2bf(v.y); o.z = f2bf(v.z); o.w = f2bf(v.w);
  reinterpret_cast<ushort4*>(out)[i] = o;
}

// ---------------- transpose + convert: in[K][N] f32 -> out[N][K] bf16 ----------------
__global__ void k_transpose_cvt(const float* __restrict__ in, uint16_t* __restrict__ out,
                                int K, int N) {
  __shared__ float tile[64][65];
  const int nb = blockIdx.x * 64, kb = blockIdx.y * 64;
  const int c = threadIdx.x & 63, r0 = threadIdx.x >> 6;
#pragma unroll
  for (int i = 0; i < 16; ++i) {
    int r = r0 * 16 + i;
    tile[r][c] = in[(size_t)(kb + r) * N + nb + c];
  }
  __syncthreads();
#pragma unroll
  for (int i = 0; i < 16; ++i) {
    int rr = r0 * 16 + i;
    out[(size_t)(nb + rr) * K + kb + c] = f2bf(tile[c][rr]);
  }
}

// ---------------- V repack: QKV[8192][3072] -> Vt[BH][64][NS] ----------------
__global__ void k_vt_repack(const uint16_t* __restrict__ qkv, uint16_t* __restrict__ vt) {
  __shared__ uint16_t tile[64][66];
  const int bh = blockIdx.y, sb = blockIdx.x * 64;
  const int b = bh >> 4, h = bh & 15;
  const int c = threadIdx.x & 63, r0 = threadIdx.x >> 6;
#pragma unroll
  for (int i = 0; i < 16; ++i) {
    int s = r0 * 16 + i;
    tile[s][c] = qkv[(size_t)(b * NS + sb + s) * 3072 + 2048 + h * 64 + c];
  }
  __syncthreads();
#pragma unroll
  for (int i = 0; i < 16; ++i) {
    int d = r0 * 16 + i;
    vt[(size_t)bh * 64 * NS + (size_t)d * NS + sb + c] = tile[c][d];
  }
}

// ---------------- GEMM: proven 128x128 m97-style ----------------
template<int OUT_BF16>
__global__ __launch_bounds__(256)
void k_gemm(const uint16_t* __restrict__ A, const uint16_t* __restrict__ Bt,
            const float* __restrict__ bias, void* __restrict__ C,
            int M, int N, int K) {
  __shared__ __align__(16) char Al[8192];
  __shared__ __align__(16) char Bl[8192];
  const int tid = threadIdx.x;
  const int wave = tid >> 6, lane = tid & 63;
  const int mb = blockIdx.y * 128, nb = blockIdx.x * 128;
  const int wm = (wave >> 1) * 64, wn = (wave & 1) * 64;
  const int fr = lane & 15, cc = lane >> 4;
  const int srow = tid >> 2, sch = tid & 3;
  f32x4 acc[4][4] = {};

  for (int kb = 0; kb < K; kb += 32) {
#pragma unroll
    for (int p = 0; p < 2; ++p) {
      int row = p * 64 + srow;
      int cg = sch ^ (row & 3) ^ ((row >> 2) & 3);
      gload_lds16(A + (size_t)(mb + row) * K + kb + cg * 8, Al + p * 4096 + wave * 1024);
      gload_lds16(Bt + (size_t)(nb + row) * K + kb + cg * 8, Bl + p * 4096 + wave * 1024);
    }
    __syncthreads();
    bf16x8 af[4], bfr[4];
#pragma unroll
    for (int i = 0; i < 4; ++i) {
      int ra = wm + i * 16 + fr;
      af[i] = *(const bf16x8*)(Al + ra * 64 + ((cc ^ (ra & 3) ^ ((ra >> 2) & 3)) * 16));
      int rb = wn + i * 16 + fr;
      bfr[i] = *(const bf16x8*)(Bl + rb * 64 + ((cc ^ (rb & 3) ^ ((rb >> 2) & 3)) * 16));
    }
#pragma unroll
    for (int i = 0; i < 4; ++i)
#pragma unroll
      for (int j = 0; j < 4; ++j)
        acc[i][j] = __builtin_amdgcn_mfma_f32_16x16x32_bf16(af[i], bfr[j], acc[i][j], 0, 0, 0);
    __syncthreads();
  }

#pragma unroll
  for (int i = 0; i < 4; ++i)
#pragma unroll
    for (int j = 0; j < 4; ++j)
#pragma unroll
      for (int r = 0; r < 4; ++r) {
        int row = mb + wm + i * 16 + cc * 4 + r;
        int col = nb + wn + j * 16 + fr;
        float v = acc[i][j][r] + bias[col];
        if (OUT_BF16)
          ((uint16_t*)C)[(size_t)row * N + col] = f2bf(v);
        else
          ((float*)C)[(size_t)row * N + col] = v;
      }
}

// ---------------- flash attention: T15 att[2] pipeline, R2-proven numerics ----------------
// Per body(t): stage(t+1) || PV(t-1) MFMA || softmax(t) VALU in one region, then
// acc-rescale (post-PV, provably consistent: both at scale m(t-1)), barrier, QK(t+1).
// K double-buffered, V triple-buffered (PV(t-1)'s V must survive stage(t+1)).
__global__ __launch_bounds__(256)
void k_attn(const uint16_t* __restrict__ qkv, const uint16_t* __restrict__ vt,
            uint16_t* __restrict__ out) {
  __shared__ __align__(16) char Kl[2][8192];  // [64 kv][64 d] bf16, chunk-XOR swizzled
  __shared__ __align__(16) char Vl[3][8192];  // [64 d][64 kv] bf16, chunk-XOR swizzled

  const int id = blockIdx.y * 16 + blockIdx.x;
  const int wfid = (id & 7) * 128 + (id >> 3);  // XCD swizzle (1024 % 8 == 0)
  const int bh = wfid >> 4, qblk = wfid & 15;
  const int b = bh >> 4, h = bh & 15;
  const int tid = threadIdx.x, wave = tid >> 6, lane = tid & 63;
  const int ln31 = lane & 31, hi = lane >> 5;

  const int q0 = qblk * 128 + wave * 32;
  const uint16_t* qrowp = qkv + (size_t)(b * NS + q0 + ln31) * 3072 + h * 64 + hi * 8;
  bf16x8 qf[4];
#pragma unroll
  for (int kk = 0; kk < 4; ++kk) qf[kk] = *(const bf16x8*)(qrowp + kk * 16);

  const int srow = tid >> 3;
  const int cs = (tid & 7) ^ (srow & 7);
  const uint16_t* ksrc = qkv + (size_t)(b * NS) * 3072 + 1024 + h * 64 + cs * 8;
  const uint16_t* vsrc = vt + (size_t)bh * 64 * NS + cs * 8;
  char* const Vbase = (char*)Vl;

  f32x16 st0, st1, acc0 = {}, acc1 = {};
  bf16x8 pfA[4], pfB[4];
  float m_run = -1e30f, l_run = 0.f;
  const float CL = 0.18033688011112042f;  // SCALE * log2(e)
  const int ksw = ln31 & 7;

  int vpv = 16384, vstage = 8192, vidle = 0;  // byte offsets of V tiles (t-1, t+1, t) % 3
  const uint16_t* kp = ksrc + (size_t)64 * 3072;  // K source for tile 1
  const uint16_t* vp = vsrc + 64;                 // V source for tile 1

#define QK_T(KB) do {                                                        \
    const char* kb0_ = Kl[KB] + ln31 * 128;                                  \
    const char* kb1_ = kb0_ + 32 * 128;                                      \
    _Pragma("unroll")                                                        \
    for (int r = 0; r < 16; ++r) { st0[r] = 0.f; st1[r] = 0.f; }             \
    __builtin_amdgcn_s_setprio(1);                                           \
    _Pragma("unroll")                                                        \
    for (int kk = 0; kk < 4; ++kk) {                                         \
      int c_ = ((kk * 2 + hi) ^ ksw) * 16;                                   \
      bf16x8 k0 = *(const bf16x8*)(kb0_ + c_);                               \
      bf16x8 k1 = *(const bf16x8*)(kb1_ + c_);                               \
      st0 = __builtin_amdgcn_mfma_f32_32x32x16_bf16(k0, qf[kk], st0, 0, 0, 0);\
      st1 = __builtin_amdgcn_mfma_f32_32x32x16_bf16(k1, qf[kk], st1, 0, 0, 0);\
    }                                                                        \
    __builtin_amdgcn_s_setprio(0);                                           \
  } while (0)

#define PV_T(PF, VOFS) do {                                                  \
    const char* vb0_ = Vbase + (VOFS) + ln31 * 128;                          \
    const char* vb1_ = vb0_ + 32 * 128;                                      \
    _Pragma("unroll")                                                        \
    for (int kkp = 0; kkp < 4; ++kkp) {                                      \
      int c_ = ((kkp * 2 + hi) ^ ksw) * 16;                                  \
      bf16x8 v0 = *(const bf16x8*)(vb0_ + c_);                               \
      bf16x8 v1 = *(const bf16x8*)(vb1_ + c_);                               \
      acc0 = __builtin_amdgcn_mfma_f32_32x32x16_bf16(v0, PF[kkp], acc0, 0, 0, 0);\
      acc1 = __builtin_amdgcn_mfma_f32_32x32x16_bf16(v1, PF[kkp], acc1, 0, 0, 0);\
    }                                                                        \
  } while (0)

#define PBUILD(DST, SRC, S2) do {                                            \
    uint32_t A0 = cvtpk(SRC[(S2) * 8 + 0], SRC[(S2) * 8 + 1]);               \
    uint32_t A1 = cvtpk(SRC[(S2) * 8 + 2], SRC[(S2) * 8 + 3]);               \
    uint32_t B0 = cvtpk(SRC[(S2) * 8 + 4], SRC[(S2) * 8 + 5]);               \
    uint32_t B1 = cvtpk(SRC[(S2) * 8 + 6], SRC[(S2) * 8 + 7]);               \
    permswap(A0, B0); permswap(A1, B1);                                      \
    u32x4 pw = {A0, A1, B0, B1};                                             \
    DST = __builtin_bit_cast(bf16x8, pw);                                    \
  } while (0)

#define BODY(PFPREV, PFCUR, KB, DOPV, DOSTAGE, DOQK) do {                    \
    if (DOSTAGE) {                                                           \
      char* kd = Kl[KB] + wave * 1024;                                       \
      char* vd = Vbase + vstage + wave * 1024;                               \
      gload_lds16(kp + (size_t)srow * 3072, kd);                             \
      gload_lds16(kp + (size_t)(srow + 32) * 3072, kd + 4096);               \
      gload_lds16(vp + (size_t)srow * NS, vd);                               \
      gload_lds16(vp + (size_t)(srow + 32) * NS, vd + 4096);                 \
      kp += (size_t)64 * 3072; vp += 64;                                     \
    }                                                                        \
    /* Region A: PV(t-1) MFMA || softmax(t) VALU (independent streams) */    \
    float mx;                                                                \
    {                                                                        \
      float m8[8];                                                           \
      _Pragma("unroll")                                                      \
      for (int r = 0; r < 8; ++r)                                            \
        m8[r] = fmaxf(fmaxf(st0[r], st0[r + 8]), fmaxf(st1[r], st1[r + 8])); \
      mx = fmaxf(fmaxf(fmaxf(m8[0], m8[4]), fmaxf(m8[1], m8[5])),            \
                 fmaxf(fmaxf(m8[2], m8[6]), fmaxf(m8[3], m8[7])));           \
    }                                                                        \
    if (DOPV) PV_T(PFPREV, vpv);                                             \
    mx = fmaxf(mx, __shfl_xor(mx, 32));                                      \
    const bool cond = __ballot(mx > m_run + 64.f) != 0;                      \
    const float m_new = cond ? fmaxf(m_run, mx) : m_run;                     \
    const float al = fexp2((m_run - m_new) * CL);  /* exactly 1.0 if !cond */\
    const float nmc = -m_new * CL;                                           \
    float rs = 0.f;                                                          \
    _Pragma("unroll")                                                        \
    for (int r = 0; r < 16; ++r) { st0[r] = fexp2(fmaf(st0[r], CL, nmc)); rs += st0[r]; } \
    _Pragma("unroll")                                                        \
    for (int r = 0; r < 16; ++r) { st1[r] = fexp2(fmaf(st1[r], CL, nmc)); rs += st1[r]; } \
    rs += __shfl_xor(rs, 32);                                                \
    PBUILD(PFCUR[0], st0, 0); PBUILD(PFCUR[1], st0, 1);                      \
    PBUILD(PFCUR[2], st1, 0); PBUILD(PFCUR[3], st1, 1);                      \
    l_run = l_run * al + rs;                                                 \
    if (cond) {  /* post-PV rescale: acc (incl. PV(t-1)) at scale m(t-1) -> m(t) */ \
      _Pragma("unroll")                                                      \
      for (int r = 0; r < 16; ++r) { acc0[r] *= al; acc1[r] *= al; }         \
    }                                                                        \
    m_run = m_new;                                                           \
    { int tmp_ = vpv; vpv = vidle; vidle = vstage; vstage = tmp_; }          \
    if (DOQK) {                                                              \
      __syncthreads();                                                       \
      QK_T(KB);                                                              \
    }                                                                        \
  } while (0)

  // prologue: stage tile 0 (K->Kl[0], V->Vl[0]), QK(0)
  gload_lds16(ksrc + (size_t)srow * 3072, Kl[0] + wave * 1024);
  gload_lds16(ksrc + (size_t)(srow + 32) * 3072, Kl[0] + wave * 1024 + 4096);
  gload_lds16(vsrc + (size_t)srow * NS, Vbase + wave * 1024);
  gload_lds16(vsrc + (size_t)(srow + 32) * NS, Vbase + wave * 1024 + 4096);
  __syncthreads();
  QK_T(0);

  BODY(pfB, pfA, 1, 0, 1, 1);  // body(0): no PV
  for (int t = 1; t < 31; t += 2) {
    BODY(pfA, pfB, 0, 1, 1, 1);  // body(t), t odd
    BODY(pfB, pfA, 1, 1, 1, 1);  // body(t+1), even
  }
  BODY(pfA, pfB, 0, 1, 0, 0);    // body(31): no stage, no barrier, no QK
  PV_T(pfB, vpv);                // PV(31)

#undef BODY
#undef PBUILD
#undef PV_T
#undef QK_T

  // epilogue: normalize, transpose O^T -> row-major via per-wave LDS scratch
  const float rl = 1.0f / l_run;
  char* sc = (char*)Kl + wave * 4096 + ln31 * 128;
  const int qsw = ln31 & 15;
#pragma unroll
  for (int dn = 0; dn < 2; ++dn) {
    const f32x16& a = dn ? acc1 : acc0;
#pragma unroll
    for (int g = 0; g < 4; ++g) {
      uint2 w;
      w.x = cvtpk(a[4 * g + 0] * rl, a[4 * g + 1] * rl);
      w.y = cvtpk(a[4 * g + 2] * rl, a[4 * g + 3] * rl);
      int c8 = (dn * 8 + 2 * g + hi) ^ qsw;
      *(uint2*)(sc + c8 * 8) = w;
    }
  }
  char* outp = (char*)out + ((size_t)(b * NS + q0 + ln31) * 1024 + h * 64 + hi * 32) * 2;
#pragma unroll
  for (int cc2 = 0; cc2 < 4; ++cc2) {
    uint2 va = *(const uint2*)(sc + (((hi * 8 + 2 * cc2 + 0) ^ qsw) * 8));
    uint2 vb2 = *(const uint2*)(sc + (((hi * 8 + 2 * cc2 + 1) ^ qsw) * 8));
    u32x4 o = {va.x, va.y, vb2.x, vb2.y};
    *(u32x4*)(outp + cc2 * 16) = o;
  }
}

extern "C" void kernel_launch(void* const* d_in, const int* in_sizes, int n_in,
                              void* d_out, int out_size, void* d_ws, size_t ws_size,
                              hipStream_t stream) {
  const float* x     = (const float*)d_in[0];
  const float* w_qkv = (const float*)d_in[1];
  const float* b_qkv = (const float*)d_in[2];
  const float* w_out = (const float*)d_in[3];
  const float* b_out = (const float*)d_in[4];
  float* out = (float*)d_out;
  char* ws = (char*)d_ws;

  uint16_t* Xb    = (uint16_t*)(ws);                // 16 MB [8192][1024] bf16 (reused as AO)
  uint16_t* Wqkvt = (uint16_t*)(ws + (16u << 20));  //  6 MB [3072][1024] bf16
  uint16_t* Woutt = (uint16_t*)(ws + (22u << 20));  //  2 MB [1024][1024] bf16
  uint16_t* QKV   = (uint16_t*)(ws + (24u << 20));  // 48 MB [8192][3072] bf16
  uint16_t* Vt    = (uint16_t*)(ws + (72u << 20));  // 16 MB [64][64][2048] bf16
  uint16_t* AO    = Xb;

  k_cvt_bf16<<<(NB * NS * ND / 4 + 255) / 256, 256, 0, stream>>>(x, Xb, NB * NS * ND / 4);
  k_transpose_cvt<<<dim3(48, 16), 256, 0, stream>>>(w_qkv, Wqkvt, ND, 3 * ND);
  k_transpose_cvt<<<dim3(16, 16), 256, 0, stream>>>(w_out, Woutt, ND, ND);
  k_gemm<1><<<dim3(24, 64), 256, 0, stream>>>(Xb, Wqkvt, b_qkv, QKV, NB * NS, 3 * ND, ND);
  k_vt_repack<<<dim3(32, 64), 256, 0, stream>>>(QKV, Vt);
  k_attn<<<dim3(16, 64), 256, 0, stream>>>(QKV, Vt, AO);
  k_gemm<0><<<dim3(8, 64), 256, 0, stream>>>(AO, Woutt, b_out, out, NB * NS, ND, ND);
}